// Round 1
// baseline (1959.236 us; speedup 1.0000x reference)
//
#include <hip/hip_runtime.h>
#include <math.h>

#define HID 1024
#define NROWS 2048

// ---------------------------------------------------------------------------
// Generic fp32 tiled GEMM: C = A @ B.  A[M,K], B[K,N], C[M,N], all row-major.
// BM=64, BN=64, BK=16, 256 threads, 4x4 per thread. Requires M%64==0, N%64==0,
// K%16==0 (true for all uses here).
// ---------------------------------------------------------------------------
__global__ __launch_bounds__(256) void gemm_f32(const float* __restrict__ A,
                                                const float* __restrict__ B,
                                                float* __restrict__ C,
                                                int M, int N, int K) {
  __shared__ float As[16][68];   // [k][m], padded: b128-aligned reads, no conflicts
  __shared__ float Bs[16][64];
  const int tid = threadIdx.x;
  const int ty = tid >> 4, tx = tid & 15;
  const int r0 = blockIdx.y * 64, c0 = blockIdx.x * 64;
  float acc[4][4] = {};
  for (int kt = 0; kt < K; kt += 16) {
#pragma unroll
    for (int i = 0; i < 4; ++i) {        // A tile 64x16 -> transposed store
      int L = tid + i * 256;
      int r = L >> 4, c = L & 15;
      As[c][r] = A[(size_t)(r0 + r) * K + kt + c];
    }
#pragma unroll
    for (int i = 0; i < 4; ++i) {        // B tile 16x64
      int L = tid + i * 256;
      int r = L >> 6, c = L & 63;
      Bs[r][c] = B[(size_t)(kt + r) * N + c0 + c];
    }
    __syncthreads();
#pragma unroll
    for (int k = 0; k < 16; ++k) {
      float a[4], b[4];
#pragma unroll
      for (int i = 0; i < 4; ++i) a[i] = As[k][ty * 4 + i];
#pragma unroll
      for (int j = 0; j < 4; ++j) b[j] = Bs[k][tx * 4 + j];
#pragma unroll
      for (int i = 0; i < 4; ++i)
#pragma unroll
        for (int j = 0; j < 4; ++j) acc[i][j] += a[i] * b[j];
    }
    __syncthreads();
  }
#pragma unroll
  for (int i = 0; i < 4; ++i)
#pragma unroll
    for (int j = 0; j < 4; ++j)
      C[(size_t)(r0 + ty * 4 + i) * N + c0 + tx * 4 + j] = acc[i][j];
}

// ---------------------------------------------------------------------------
// Fused logits GEMM + partial online-softmax.
// Computes L = P @ W + bias over a 64-row x 128-col tile, reduces per row to
// (max, sum exp(l - max)) and writes partials[row, colsplit].
// P [NROWS, Kd], W [Kd, Ncols], bias [Ncols]. Kd % 8 == 0, NROWS % 64 == 0.
// ---------------------------------------------------------------------------
__global__ __launch_bounds__(256) void logit_pass(const float* __restrict__ P,
                                                  const float* __restrict__ W,
                                                  const float* __restrict__ bias,
                                                  float* __restrict__ pm,
                                                  float* __restrict__ ps,
                                                  int Kd, int Ncols, int nsplit) {
  __shared__ float As[8][68];     // [k][m]
  __shared__ float Bs[8][128];    // [k][n]
  __shared__ float redm[64][17];
  __shared__ float reds[64][17];
  const int tid = threadIdx.x;
  const int ty = tid >> 4, tx = tid & 15;
  const int r0 = blockIdx.y * 64;
  const int c0 = blockIdx.x * 128;
  float acc[4][8] = {};
  for (int kt = 0; kt < Kd; kt += 8) {
#pragma unroll
    for (int i = 0; i < 2; ++i) {        // A tile 64x8 -> transposed
      int L = tid + i * 256;
      int r = L >> 3, c = L & 7;
      As[c][r] = P[(size_t)(r0 + r) * Kd + kt + c];
    }
#pragma unroll
    for (int i = 0; i < 4; ++i) {        // B tile 8x128
      int L = tid + i * 256;
      int r = L >> 7, c = L & 127;
      int col = c0 + c;
      Bs[r][c] = (col < Ncols) ? W[(size_t)(kt + r) * Ncols + col] : 0.f;
    }
    __syncthreads();
#pragma unroll
    for (int k = 0; k < 8; ++k) {
      float a[4], b[8];
#pragma unroll
      for (int i = 0; i < 4; ++i) a[i] = As[k][ty * 4 + i];
#pragma unroll
      for (int j = 0; j < 8; ++j) b[j] = Bs[k][tx * 8 + j];
#pragma unroll
      for (int i = 0; i < 4; ++i)
#pragma unroll
        for (int j = 0; j < 8; ++j) acc[i][j] += a[i] * b[j];
    }
    __syncthreads();
  }
  // epilogue: per-thread (4 rows x 8 cols) -> per-row (m, s), then across tx
#pragma unroll
  for (int tm = 0; tm < 4; ++tm) {
    float mt = -3.0e38f, st = 0.f;
#pragma unroll
    for (int tn = 0; tn < 8; ++tn) {
      int col = c0 + tx * 8 + tn;
      if (col < Ncols) mt = fmaxf(mt, acc[tm][tn] + bias[col]);
    }
#pragma unroll
    for (int tn = 0; tn < 8; ++tn) {
      int col = c0 + tx * 8 + tn;
      if (col < Ncols) st += __expf(acc[tm][tn] + bias[col] - mt);
    }
    redm[ty * 4 + tm][tx] = mt;
    reds[ty * 4 + tm][tx] = st;
  }
  __syncthreads();
  if (tid < 64) {
    float M = -3.0e38f;
#pragma unroll
    for (int j = 0; j < 16; ++j) M = fmaxf(M, redm[tid][j]);
    float S = 0.f;
#pragma unroll
    for (int j = 0; j < 16; ++j) S += reds[tid][j] * __expf(redm[tid][j] - M);
    pm[(size_t)(r0 + tid) * nsplit + blockIdx.x] = M;
    ps[(size_t)(r0 + tid) * nsplit + blockIdx.x] = S;
  }
}

// ---------------------------------------------------------------------------
// Finalize: one wave (64 lanes) per row. Merges partials into the row LSE,
// computes the two cluster logits, the single target logit, and emits nll.
// ---------------------------------------------------------------------------
__device__ __forceinline__ float wave_sum(float a) {
#pragma unroll
  for (int off = 32; off; off >>= 1) a += __shfl_xor(a, off, 64);
  return a;
}

__global__ __launch_bounds__(256) void finalize(
    const float* __restrict__ P0, const float* __restrict__ P1,
    const float* __restrict__ P2,
    const float* __restrict__ Wl0, const float* __restrict__ bl0,
    const float* __restrict__ Wl1, const float* __restrict__ bl1,
    const float* __restrict__ Wl2, const float* __restrict__ bl2,
    const float* __restrict__ Wc, const float* __restrict__ bc,
    const int* __restrict__ y,
    const float* __restrict__ pmh, const float* __restrict__ psh, int nsh,
    const float* __restrict__ pm1, const float* __restrict__ ps1, int ns1,
    const float* __restrict__ pm2, const float* __restrict__ ps2, int ns2,
    float* __restrict__ out) {
  const int lane = threadIdx.x & 63;
  const int row = blockIdx.x * 4 + (threadIdx.x >> 6);

  // cluster logits: c = P0[row] @ Wc + bc
  float a0 = 0.f, a1 = 0.f;
  for (int k = lane; k < HID; k += 64) {
    float p = P0[(size_t)row * HID + k];
    a0 += p * Wc[2 * k];
    a1 += p * Wc[2 * k + 1];
  }
  a0 = wave_sum(a0);
  a1 = wave_sum(a1);
  const float cl0 = a0 + bc[0], cl1 = a1 + bc[1];

  // head LSE: merge partials across lanes, then butterfly
  float m = -3.0e38f, s = 0.f;
  for (int i = lane; i < nsh; i += 64) {
    float mi = pmh[(size_t)row * nsh + i];
    float si = psh[(size_t)row * nsh + i];
    float M = fmaxf(m, mi);
    s = s * __expf(m - M) + si * __expf(mi - M);
    m = M;
  }
#pragma unroll
  for (int off = 32; off; off >>= 1) {
    float mo = __shfl_xor(m, off, 64), so = __shfl_xor(s, off, 64);
    float M = fmaxf(m, mo);
    s = s * __expf(m - M) + so * __expf(mo - M);
    m = M;
  }
  {  // fold in the two cluster columns (they are part of head softmax)
    float M = fmaxf(m, fmaxf(cl0, cl1));
    s = s * __expf(m - M) + __expf(cl0 - M) + __expf(cl1 - M);
    m = M;
  }
  const float lse = m + logf(s);

  const int yy = y[row];
  float nll;
  if (yy < 10000) {
    float a = 0.f;
    for (int k = lane; k < HID; k += 64)
      a += P0[(size_t)row * HID + k] * Wl0[(size_t)k * 10000 + yy];
    a = wave_sum(a);
    nll = -((a + bl0[yy]) - lse);
  } else if (yy < 20000) {
    const int t = yy - 10000;
    float m2 = -3.0e38f, s2 = 0.f;
    for (int i = lane; i < ns1; i += 64) {
      float mi = pm1[(size_t)row * ns1 + i];
      float si = ps1[(size_t)row * ns1 + i];
      float M = fmaxf(m2, mi);
      s2 = s2 * __expf(m2 - M) + si * __expf(mi - M);
      m2 = M;
    }
#pragma unroll
    for (int off = 32; off; off >>= 1) {
      float mo = __shfl_xor(m2, off, 64), so = __shfl_xor(s2, off, 64);
      float M = fmaxf(m2, mo);
      s2 = s2 * __expf(m2 - M) + so * __expf(mo - M);
      m2 = M;
    }
    const float lse1 = m2 + logf(s2);
    float a = 0.f;
    for (int k = lane; k < 256; k += 64)
      a += P1[(size_t)row * 256 + k] * Wl1[(size_t)k * 30000 + t];
    a = wave_sum(a);
    // head_lp[:, -1] == cluster col 1
    nll = -((cl1 - lse) + ((a + bl1[t]) - lse1));
  } else {
    const int t = yy - 20000;
    float m2 = -3.0e38f, s2 = 0.f;
    for (int i = lane; i < ns2; i += 64) {
      float mi = pm2[(size_t)row * ns2 + i];
      float si = ps2[(size_t)row * ns2 + i];
      float M = fmaxf(m2, mi);
      s2 = s2 * __expf(m2 - M) + si * __expf(mi - M);
      m2 = M;
    }
#pragma unroll
    for (int off = 32; off; off >>= 1) {
      float mo = __shfl_xor(m2, off, 64), so = __shfl_xor(s2, off, 64);
      float M = fmaxf(m2, mo);
      s2 = s2 * __expf(m2 - M) + so * __expf(mo - M);
      m2 = M;
    }
    const float lse2 = m2 + logf(s2);
    float a = (lane < 64) ? 0.f : 0.f;
    for (int k = lane; k < 64; k += 64)
      a += P2[(size_t)row * 64 + k] * Wl2[(size_t)k * 52000 + t];
    a = wave_sum(a);
    // head_lp[:, -2] == cluster col 0
    nll = -((cl0 - lse) + ((a + bl2[t]) - lse2));
  }
  if (lane == 0) out[row] = nll;
}

// ---------------------------------------------------------------------------
extern "C" void kernel_launch(void* const* d_in, const int* in_sizes, int n_in,
                              void* d_out, int out_size, void* d_ws, size_t ws_size,
                              hipStream_t stream) {
  const float* x   = (const float*)d_in[0];
  const int*   y   = (const int*)d_in[1];
  const float* Wp0 = (const float*)d_in[2];
  const float* Wp1 = (const float*)d_in[3];
  const float* Wp2 = (const float*)d_in[4];
  const float* Wl0 = (const float*)d_in[5];
  const float* bl0 = (const float*)d_in[6];
  const float* Wl1 = (const float*)d_in[7];
  const float* bl1 = (const float*)d_in[8];
  const float* Wl2 = (const float*)d_in[9];
  const float* bl2 = (const float*)d_in[10];
  const float* Wc  = (const float*)d_in[11];
  const float* bc  = (const float*)d_in[12];
  float* out = (float*)d_out;

  float* ws = (float*)d_ws;
  float* P0 = ws;                       // 2048*1024
  float* P1 = P0 + (size_t)NROWS * 1024;
  float* P2 = P1 + (size_t)NROWS * 256;
  const int nsh = (10000 + 127) / 128;  // 79
  const int ns1 = (30000 + 127) / 128;  // 235
  const int ns2 = (52000 + 127) / 128;  // 407
  float* pmh = P2 + (size_t)NROWS * 64;
  float* psh = pmh + (size_t)NROWS * nsh;
  float* pm1 = psh + (size_t)NROWS * nsh;
  float* ps1 = pm1 + (size_t)NROWS * ns1;
  float* pm2 = ps1 + (size_t)NROWS * ns1;
  float* ps2 = pm2 + (size_t)NROWS * ns2;

  dim3 blk(256);
  // projections
  gemm_f32<<<dim3(1024 / 64, NROWS / 64), blk, 0, stream>>>(x, Wp0, P0, NROWS, 1024, 1024);
  gemm_f32<<<dim3(256 / 64,  NROWS / 64), blk, 0, stream>>>(x, Wp1, P1, NROWS, 256, 1024);
  gemm_f32<<<dim3(64 / 64,   NROWS / 64), blk, 0, stream>>>(x, Wp2, P2, NROWS, 64, 1024);
  // fused logits + partial softmax
  logit_pass<<<dim3(nsh, NROWS / 64), blk, 0, stream>>>(P0, Wl0, bl0, pmh, psh, 1024, 10000, nsh);
  logit_pass<<<dim3(ns1, NROWS / 64), blk, 0, stream>>>(P1, Wl1, bl1, pm1, ps1, 256, 30000, ns1);
  logit_pass<<<dim3(ns2, NROWS / 64), blk, 0, stream>>>(P2, Wl2, bl2, pm2, ps2, 64, 52000, ns2);
  // merge + target logits + nll
  finalize<<<dim3(NROWS / 4), blk, 0, stream>>>(P0, P1, P2, Wl0, bl0, Wl1, bl1,
                                                Wl2, bl2, Wc, bc, y,
                                                pmh, psh, nsh, pm1, ps1, ns1,
                                                pm2, ps2, ns2, out);
}

// Round 2
// 580.721 us; speedup vs baseline: 3.3738x; 3.3738x over previous
//
#include <hip/hip_runtime.h>
#include <math.h>

#define HID 1024
#define NROWS 2048

typedef __attribute__((ext_vector_type(8))) short short8;   // 8 bf16 = 4 VGPRs
typedef __attribute__((ext_vector_type(4))) short short4_t;
typedef __attribute__((ext_vector_type(4))) float f32x4;

__device__ __forceinline__ short f2bf(float f) {
  union { float f; unsigned u; } v; v.f = f;
  unsigned r = v.u + 0x7fffu + ((v.u >> 16) & 1u);
  return (short)(r >> 16);
}

// ---------------------------------------------------------------------------
// x fp32 -> bf16 (row-major copy)
// ---------------------------------------------------------------------------
__global__ __launch_bounds__(256) void cvt_bf16(const float* __restrict__ X,
                                                short* __restrict__ Xb) {
  int i = (blockIdx.x * 256 + threadIdx.x) * 4;
  short4_t o;
  o.x = f2bf(X[i + 0]); o.y = f2bf(X[i + 1]);
  o.z = f2bf(X[i + 2]); o.w = f2bf(X[i + 3]);
  *(short4_t*)&Xb[i] = o;
}

// ---------------------------------------------------------------------------
// W fp32 [K,N] -> BT bf16 [Npad,K], rows n>=N zero-filled. 32x32 LDS tiles.
// ---------------------------------------------------------------------------
__global__ __launch_bounds__(256) void transpose_cvt(const float* __restrict__ W,
                                                     short* __restrict__ BT,
                                                     int K, int N, int Npad) {
  __shared__ float T[32][33];
  const int tid = threadIdx.x;
  const int n0 = blockIdx.x * 32, k0 = blockIdx.y * 32;
  const int r = tid >> 3, c = (tid & 7) * 4;
  float v0 = 0.f, v1 = 0.f, v2 = 0.f, v3 = 0.f;
  const float* p = &W[(size_t)(k0 + r) * N];
  if (n0 + c + 3 < N) {
    v0 = p[n0 + c]; v1 = p[n0 + c + 1]; v2 = p[n0 + c + 2]; v3 = p[n0 + c + 3];
  } else {
    if (n0 + c + 0 < N) v0 = p[n0 + c + 0];
    if (n0 + c + 1 < N) v1 = p[n0 + c + 1];
    if (n0 + c + 2 < N) v2 = p[n0 + c + 2];
    if (n0 + c + 3 < N) v3 = p[n0 + c + 3];
  }
  T[r][c] = v0; T[r][c + 1] = v1; T[r][c + 2] = v2; T[r][c + 3] = v3;
  __syncthreads();
  const int nl = tid >> 3, kl = (tid & 7) * 4;
  const int n = n0 + nl;
  if (n < Npad) {
    short4_t o;
    o.x = (n < N) ? f2bf(T[kl + 0][nl]) : (short)0;
    o.y = (n < N) ? f2bf(T[kl + 1][nl]) : (short)0;
    o.z = (n < N) ? f2bf(T[kl + 2][nl]) : (short)0;
    o.w = (n < N) ? f2bf(T[kl + 3][nl]) : (short)0;
    *(short4_t*)&BT[(size_t)n * K + k0 + kl] = o;
  }
}

// ---------------------------------------------------------------------------
// MFMA main-loop macro bits shared by proj/logit kernels.
// Tile: 128 rows x 128 cols, BK=32, 4 waves (2x2), each wave 64x64 via 4x4
// mfma_f32_16x16x32_bf16. A [M,K] bf16 row-major, BT [Npad,K] bf16 row-major.
// ---------------------------------------------------------------------------
__device__ __forceinline__ void mfma_mainloop(const short* __restrict__ A,
                                              const short* __restrict__ BT,
                                              short* As, short* Bs,
                                              f32x4 acc[4][4],
                                              int K, int r0, int c0,
                                              int w, int lane) {
  const int quad = lane >> 4, ln = lane & 15;
  const int wm = w >> 1, wn = w & 1;
  const int lrow = lane >> 2;         // 0..15
  const int lcol = (lane & 3) * 8;    // 0,8,16,24
  for (int kt = 0; kt < K; kt += 32) {
#pragma unroll
    for (int i = 0; i < 2; ++i) {
      const int b = w * 2 + i;
      const short* ga = A + (size_t)(r0 + b * 16 + lrow) * K + kt + lcol;
      __builtin_amdgcn_global_load_lds(
          (const __attribute__((address_space(1))) void*)ga,
          (__attribute__((address_space(3))) void*)(As + b * 512), 16, 0, 0);
      const short* gb = BT + (size_t)(c0 + b * 16 + lrow) * K + kt + lcol;
      __builtin_amdgcn_global_load_lds(
          (const __attribute__((address_space(1))) void*)gb,
          (__attribute__((address_space(3))) void*)(Bs + b * 512), 16, 0, 0);
    }
    __syncthreads();
    short8 af[4], bf[4];
#pragma unroll
    for (int mt = 0; mt < 4; ++mt)
      af[mt] = *(const short8*)(As + (wm * 64 + mt * 16 + ln) * 32 + quad * 8);
#pragma unroll
    for (int nt = 0; nt < 4; ++nt)
      bf[nt] = *(const short8*)(Bs + (wn * 64 + nt * 16 + ln) * 32 + quad * 8);
#pragma unroll
    for (int mt = 0; mt < 4; ++mt)
#pragma unroll
      for (int nt = 0; nt < 4; ++nt)
        acc[mt][nt] = __builtin_amdgcn_mfma_f32_16x16x32_bf16(
            af[mt], bf[nt], acc[mt][nt], 0, 0, 0);
    __syncthreads();
  }
}

// C/D layout: col = lane&15, row = (lane>>4)*4 + reg   [verified m89/m91]

// Projection GEMM: C fp32 + Cb bf16 = A @ BT^T, col guard < N.
__global__ __launch_bounds__(256) void proj_mfma(const short* __restrict__ A,
                                                 const short* __restrict__ BT,
                                                 float* __restrict__ C,
                                                 short* __restrict__ Cb,
                                                 int K, int N) {
  __shared__ short As[128 * 32];
  __shared__ short Bs[128 * 32];
  const int tid = threadIdx.x;
  const int w = tid >> 6, lane = tid & 63;
  const int quad = lane >> 4, ln = lane & 15;
  const int wm = w >> 1, wn = w & 1;
  const int r0 = blockIdx.y * 128, c0 = blockIdx.x * 128;
  f32x4 acc[4][4];
  const f32x4 zero = {0.f, 0.f, 0.f, 0.f};
#pragma unroll
  for (int i = 0; i < 4; ++i)
#pragma unroll
    for (int j = 0; j < 4; ++j) acc[i][j] = zero;
  mfma_mainloop(A, BT, As, Bs, acc, K, r0, c0, w, lane);
#pragma unroll
  for (int mt = 0; mt < 4; ++mt)
#pragma unroll
    for (int r = 0; r < 4; ++r) {
      const int grow = r0 + wm * 64 + mt * 16 + quad * 4 + r;
#pragma unroll
      for (int nt = 0; nt < 4; ++nt) {
        const int cg = c0 + wn * 64 + nt * 16 + ln;
        if (cg < N) {
          const float vv = acc[mt][nt][r];
          C[(size_t)grow * N + cg] = vv;
          Cb[(size_t)grow * N + cg] = f2bf(vv);
        }
      }
    }
}

// Fused logits GEMM + per-(row, 128-col-tile) online-softmax partials.
__global__ __launch_bounds__(256) void logit_mfma(const short* __restrict__ A,
                                                  const short* __restrict__ BT,
                                                  const float* __restrict__ bias,
                                                  float* __restrict__ pm,
                                                  float* __restrict__ ps,
                                                  int K, int Ncols) {
  __shared__ short As[128 * 32];
  __shared__ short Bs[128 * 32];
  __shared__ float pmL[2][128];
  __shared__ float psL[2][128];
  const int tid = threadIdx.x;
  const int w = tid >> 6, lane = tid & 63;
  const int quad = lane >> 4, ln = lane & 15;
  const int wm = w >> 1, wn = w & 1;
  const int r0 = blockIdx.y * 128, c0 = blockIdx.x * 128;
  const int nsplit = gridDim.x;
  f32x4 acc[4][4];
  const f32x4 zero = {0.f, 0.f, 0.f, 0.f};
#pragma unroll
  for (int i = 0; i < 4; ++i)
#pragma unroll
    for (int j = 0; j < 4; ++j) acc[i][j] = zero;
  mfma_mainloop(A, BT, As, Bs, acc, K, r0, c0, w, lane);
  // epilogue: per-row (max, sumexp) across this wave's 64 cols
#pragma unroll
  for (int mt = 0; mt < 4; ++mt)
#pragma unroll
    for (int r = 0; r < 4; ++r) {
      const int row_local = wm * 64 + mt * 16 + quad * 4 + r;
      float v[4];
#pragma unroll
      for (int nt = 0; nt < 4; ++nt) {
        const int cg = c0 + wn * 64 + nt * 16 + ln;
        v[nt] = (cg < Ncols) ? acc[mt][nt][r] + bias[cg] : -3.0e38f;
      }
      float mrow = fmaxf(fmaxf(v[0], v[1]), fmaxf(v[2], v[3]));
      float srow = 0.f;
#pragma unroll
      for (int nt = 0; nt < 4; ++nt) {
        const int cg = c0 + wn * 64 + nt * 16 + ln;
        if (cg < Ncols) srow += __expf(v[nt] - mrow);
      }
#pragma unroll
      for (int off = 1; off < 16; off <<= 1) {
        const float mo = __shfl_xor(mrow, off, 64);
        const float so = __shfl_xor(srow, off, 64);
        const float M = fmaxf(mrow, mo);
        srow = srow * __expf(mrow - M) + so * __expf(mo - M);
        mrow = M;
      }
      if (ln == 0) { pmL[wn][row_local] = mrow; psL[wn][row_local] = srow; }
    }
  __syncthreads();
  if (tid < 128) {
    const float m0 = pmL[0][tid], s0 = psL[0][tid];
    const float m1 = pmL[1][tid], s1 = psL[1][tid];
    const float M = fmaxf(m0, m1);
    const float S = s0 * __expf(m0 - M) + s1 * __expf(m1 - M);
    pm[(size_t)(r0 + tid) * nsplit + blockIdx.x] = M;
    ps[(size_t)(r0 + tid) * nsplit + blockIdx.x] = S;
  }
}

// ---------------------------------------------------------------------------
// Finalize: one wave per row (unchanged from round 1 — verified correct).
// ---------------------------------------------------------------------------
__device__ __forceinline__ float wave_sum(float a) {
#pragma unroll
  for (int off = 32; off; off >>= 1) a += __shfl_xor(a, off, 64);
  return a;
}

__global__ __launch_bounds__(256) void finalize(
    const float* __restrict__ P0, const float* __restrict__ P1,
    const float* __restrict__ P2,
    const float* __restrict__ Wl0, const float* __restrict__ bl0,
    const float* __restrict__ Wl1, const float* __restrict__ bl1,
    const float* __restrict__ Wl2, const float* __restrict__ bl2,
    const float* __restrict__ Wc, const float* __restrict__ bc,
    const int* __restrict__ y,
    const float* __restrict__ pmh, const float* __restrict__ psh, int nsh,
    const float* __restrict__ pm1, const float* __restrict__ ps1, int ns1,
    const float* __restrict__ pm2, const float* __restrict__ ps2, int ns2,
    float* __restrict__ out) {
  const int lane = threadIdx.x & 63;
  const int row = blockIdx.x * 4 + (threadIdx.x >> 6);

  float a0 = 0.f, a1 = 0.f;
  for (int k = lane; k < HID; k += 64) {
    const float p = P0[(size_t)row * HID + k];
    a0 += p * Wc[2 * k];
    a1 += p * Wc[2 * k + 1];
  }
  a0 = wave_sum(a0);
  a1 = wave_sum(a1);
  const float cl0 = a0 + bc[0], cl1 = a1 + bc[1];

  float m = -3.0e38f, s = 0.f;
  for (int i = lane; i < nsh; i += 64) {
    const float mi = pmh[(size_t)row * nsh + i];
    const float si = psh[(size_t)row * nsh + i];
    const float M = fmaxf(m, mi);
    s = s * __expf(m - M) + si * __expf(mi - M);
    m = M;
  }
#pragma unroll
  for (int off = 32; off; off >>= 1) {
    const float mo = __shfl_xor(m, off, 64), so = __shfl_xor(s, off, 64);
    const float M = fmaxf(m, mo);
    s = s * __expf(m - M) + so * __expf(mo - M);
    m = M;
  }
  {
    const float M = fmaxf(m, fmaxf(cl0, cl1));
    s = s * __expf(m - M) + __expf(cl0 - M) + __expf(cl1 - M);
    m = M;
  }
  const float lse = m + logf(s);

  const int yy = y[row];
  float nll;
  if (yy < 10000) {
    float a = 0.f;
    for (int k = lane; k < HID; k += 64)
      a += P0[(size_t)row * HID + k] * Wl0[(size_t)k * 10000 + yy];
    a = wave_sum(a);
    nll = -((a + bl0[yy]) - lse);
  } else if (yy < 20000) {
    const int t = yy - 10000;
    float m2 = -3.0e38f, s2 = 0.f;
    for (int i = lane; i < ns1; i += 64) {
      const float mi = pm1[(size_t)row * ns1 + i];
      const float si = ps1[(size_t)row * ns1 + i];
      const float M = fmaxf(m2, mi);
      s2 = s2 * __expf(m2 - M) + si * __expf(mi - M);
      m2 = M;
    }
#pragma unroll
    for (int off = 32; off; off >>= 1) {
      const float mo = __shfl_xor(m2, off, 64), so = __shfl_xor(s2, off, 64);
      const float M = fmaxf(m2, mo);
      s2 = s2 * __expf(m2 - M) + so * __expf(mo - M);
      m2 = M;
    }
    const float lse1 = m2 + logf(s2);
    float a = 0.f;
    for (int k = lane; k < 256; k += 64)
      a += P1[(size_t)row * 256 + k] * Wl1[(size_t)k * 30000 + t];
    a = wave_sum(a);
    nll = -((cl1 - lse) + ((a + bl1[t]) - lse1));
  } else {
    const int t = yy - 20000;
    float m2 = -3.0e38f, s2 = 0.f;
    for (int i = lane; i < ns2; i += 64) {
      const float mi = pm2[(size_t)row * ns2 + i];
      const float si = ps2[(size_t)row * ns2 + i];
      const float M = fmaxf(m2, mi);
      s2 = s2 * __expf(m2 - M) + si * __expf(mi - M);
      m2 = M;
    }
#pragma unroll
    for (int off = 32; off; off >>= 1) {
      const float mo = __shfl_xor(m2, off, 64), so = __shfl_xor(s2, off, 64);
      const float M = fmaxf(m2, mo);
      s2 = s2 * __expf(m2 - M) + so * __expf(mo - M);
      m2 = M;
    }
    const float lse2 = m2 + logf(s2);
    float a = 0.f;
    for (int k = lane; k < 64; k += 64)
      a += P2[(size_t)row * 64 + k] * Wl2[(size_t)k * 52000 + t];
    a = wave_sum(a);
    nll = -((cl0 - lse) + ((a + bl2[t]) - lse2));
  }
  if (lane == 0) out[row] = nll;
}

// ---------------------------------------------------------------------------
extern "C" void kernel_launch(void* const* d_in, const int* in_sizes, int n_in,
                              void* d_out, int out_size, void* d_ws, size_t ws_size,
                              hipStream_t stream) {
  const float* x   = (const float*)d_in[0];
  const int*   y   = (const int*)d_in[1];
  const float* Wp0 = (const float*)d_in[2];
  const float* Wp1 = (const float*)d_in[3];
  const float* Wp2 = (const float*)d_in[4];
  const float* Wl0 = (const float*)d_in[5];
  const float* bl0 = (const float*)d_in[6];
  const float* Wl1 = (const float*)d_in[7];
  const float* bl1 = (const float*)d_in[8];
  const float* Wl2 = (const float*)d_in[9];
  const float* bl2 = (const float*)d_in[10];
  const float* Wc  = (const float*)d_in[11];
  const float* bc  = (const float*)d_in[12];
  float* out = (float*)d_out;

  const int nsh = 79;   // ceil(10000/128)
  const int ns1 = 235;  // ceil(30000/128)
  const int ns2 = 407;  // ceil(52000/128)
  const int NP0 = nsh * 128, NP1 = ns1 * 128, NP2 = ns2 * 128;

  // ---- workspace layout (fp32 first, then bf16; all chunks 16B-aligned) ----
  float* ws = (float*)d_ws;
  float* P0  = ws;                      ws += (size_t)NROWS * 1024;
  float* P1  = ws;                      ws += (size_t)NROWS * 256;
  float* P2  = ws;                      ws += (size_t)NROWS * 64;
  float* pmh = ws;                      ws += (size_t)NROWS * nsh;
  float* psh = ws;                      ws += (size_t)NROWS * nsh;
  float* pm1 = ws;                      ws += (size_t)NROWS * ns1;
  float* ps1 = ws;                      ws += (size_t)NROWS * ns1;
  float* pm2 = ws;                      ws += (size_t)NROWS * ns2;
  float* ps2 = ws;                      ws += (size_t)NROWS * ns2;
  short* sp = (short*)ws;
  short* xb    = sp;                    sp += (size_t)NROWS * 1024;
  short* P0b   = sp;                    sp += (size_t)NROWS * 1024;
  short* P1b   = sp;                    sp += (size_t)NROWS * 256;
  short* P2b   = sp;                    sp += (size_t)NROWS * 64;
  short* WpT0  = sp;                    sp += (size_t)1024 * 1024;
  short* WpT1  = sp;                    sp += (size_t)256 * 1024;
  short* WpT2  = sp;                    sp += (size_t)128 * 1024;   // 64 padded to 128
  short* WlT0  = sp;                    sp += (size_t)NP0 * 1024;
  short* WlT1  = sp;                    sp += (size_t)NP1 * 256;
  short* WlT2  = sp;                    sp += (size_t)NP2 * 64;

  dim3 blk(256);
  // convert + transpose weights to bf16
  cvt_bf16<<<dim3((NROWS * 1024) / 1024), blk, 0, stream>>>(x, xb);
  transpose_cvt<<<dim3(1024 / 32, 1024 / 32), blk, 0, stream>>>(Wp0, WpT0, 1024, 1024, 1024);
  transpose_cvt<<<dim3(256 / 32, 1024 / 32), blk, 0, stream>>>(Wp1, WpT1, 1024, 256, 256);
  transpose_cvt<<<dim3(128 / 32, 1024 / 32), blk, 0, stream>>>(Wp2, WpT2, 1024, 64, 128);
  transpose_cvt<<<dim3(NP0 / 32, 1024 / 32), blk, 0, stream>>>(Wl0, WlT0, 1024, 10000, NP0);
  transpose_cvt<<<dim3(NP1 / 32, 256 / 32), blk, 0, stream>>>(Wl1, WlT1, 256, 30000, NP1);
  transpose_cvt<<<dim3(NP2 / 32, 64 / 32), blk, 0, stream>>>(Wl2, WlT2, 64, 52000, NP2);
  // projections (MFMA)
  proj_mfma<<<dim3(1024 / 128, NROWS / 128), blk, 0, stream>>>(xb, WpT0, P0, P0b, 1024, 1024);
  proj_mfma<<<dim3(256 / 128, NROWS / 128), blk, 0, stream>>>(xb, WpT1, P1, P1b, 1024, 256);
  proj_mfma<<<dim3(1, NROWS / 128), blk, 0, stream>>>(xb, WpT2, P2, P2b, 1024, 64);
  // fused logits + partial softmax (MFMA)
  logit_mfma<<<dim3(nsh, NROWS / 128), blk, 0, stream>>>(P0b, WlT0, bl0, pmh, psh, 1024, 10000);
  logit_mfma<<<dim3(ns1, NROWS / 128), blk, 0, stream>>>(P1b, WlT1, bl1, pm1, ps1, 256, 30000);
  logit_mfma<<<dim3(ns2, NROWS / 128), blk, 0, stream>>>(P2b, WlT2, bl2, pm2, ps2, 64, 52000);
  // merge + target logits + nll
  finalize<<<dim3(NROWS / 4), blk, 0, stream>>>(P0, P1, P2, Wl0, bl0, Wl1, bl1,
                                                Wl2, bl2, Wc, bc, y,
                                                pmh, psh, nsh, pm1, ps1, ns1,
                                                pm2, ps2, ns2, out);
}

// Round 3
// 424.175 us; speedup vs baseline: 4.6189x; 1.3691x over previous
//
#include <hip/hip_runtime.h>
#include <math.h>

#define HID 1024
#define NROWS 2048

typedef __attribute__((ext_vector_type(8))) short short8;
typedef __attribute__((ext_vector_type(4))) short short4_t;
typedef __attribute__((ext_vector_type(4))) float f32x4;

__device__ __forceinline__ short f2bf(float f) {
  union { float f; unsigned u; } v; v.f = f;
  unsigned r = v.u + 0x7fffu + ((v.u >> 16) & 1u);
  return (short)(r >> 16);
}
__device__ __forceinline__ float bf2f(short s) {
  union { unsigned u; float f; } v; v.u = ((unsigned)(unsigned short)s) << 16;
  return v.f;
}

// ---------------------------------------------------------------------------
// classify rows by cluster; build compacted slot lists. Single block.
// ---------------------------------------------------------------------------
__global__ __launch_bounds__(1024) void classify(const int* __restrict__ y,
                                                 int* __restrict__ counts,
                                                 int* __restrict__ slot_of_row,
                                                 int* __restrict__ rows1,
                                                 int* __restrict__ rows2) {
  __shared__ int c1, c2;
  if (threadIdx.x == 0) { c1 = 0; c2 = 0; }
  __syncthreads();
  for (int r = threadIdx.x; r < NROWS; r += 1024) {
    const int yy = y[r];
    if (yy >= 20000) {
      const int s = atomicAdd(&c2, 1);
      slot_of_row[r] = s; rows2[s] = r;
    } else if (yy >= 10000) {
      const int s = atomicAdd(&c1, 1);
      slot_of_row[r] = s; rows1[s] = r;
    } else {
      slot_of_row[r] = -1;
    }
  }
  __syncthreads();
  if (threadIdx.x == 0) { counts[0] = NROWS; counts[1] = c1; counts[2] = c2; }
}

// ---------------------------------------------------------------------------
// x fp32 -> bf16
// ---------------------------------------------------------------------------
__global__ __launch_bounds__(256) void cvt_bf16(const float* __restrict__ X,
                                                short* __restrict__ Xb) {
  const int i = (blockIdx.x * 256 + threadIdx.x) * 4;
  short4_t o;
  o.x = f2bf(X[i + 0]); o.y = f2bf(X[i + 1]);
  o.z = f2bf(X[i + 2]); o.w = f2bf(X[i + 3]);
  *(short4_t*)&Xb[i] = o;
}

// ---------------------------------------------------------------------------
// All six weight transposes (fp32 [K,N] -> bf16 [Npad,K]) in ONE launch.
// Block counts are compile-time: 1024, 256, 128, 10112, 7520, 3256 = 22296.
// ---------------------------------------------------------------------------
__global__ __launch_bounds__(256) void transpose_all(
    const float* __restrict__ Wp0, const float* __restrict__ Wp1,
    const float* __restrict__ Wp2, const float* __restrict__ Wl0,
    const float* __restrict__ Wl1, const float* __restrict__ Wl2,
    short* __restrict__ T0, short* __restrict__ T1, short* __restrict__ T2,
    short* __restrict__ T3, short* __restrict__ T4, short* __restrict__ T5) {
  int b = blockIdx.x;
  const float* W; short* BT; int K, N, Npad, tn;
  if (b < 1024)               { W = Wp0; BT = T0; K = 1024; N = 1024;  Npad = 1024;  tn = 32;   }
  else if ((b -= 1024) < 256) { W = Wp1; BT = T1; K = 1024; N = 256;   Npad = 256;   tn = 8;    }
  else if ((b -= 256) < 128)  { W = Wp2; BT = T2; K = 1024; N = 64;    Npad = 128;   tn = 4;    }
  else if ((b -= 128) < 10112){ W = Wl0; BT = T3; K = 1024; N = 10000; Npad = 10112; tn = 316;  }
  else if ((b -= 10112) < 7520){W = Wl1; BT = T4; K = 256;  N = 30000; Npad = 30080; tn = 940;  }
  else { b -= 7520;             W = Wl2; BT = T5; K = 64;   N = 52000; Npad = 52096; tn = 1628; }

  __shared__ float T[32][33];
  const int tid = threadIdx.x;
  const int n0 = (b % tn) * 32, k0 = (b / tn) * 32;
  const int r = tid >> 3, c = (tid & 7) * 4;
  float v0 = 0.f, v1 = 0.f, v2 = 0.f, v3 = 0.f;
  const float* p = &W[(size_t)(k0 + r) * N];
  if (n0 + c + 3 < N) {
    v0 = p[n0 + c]; v1 = p[n0 + c + 1]; v2 = p[n0 + c + 2]; v3 = p[n0 + c + 3];
  } else {
    if (n0 + c + 0 < N) v0 = p[n0 + c + 0];
    if (n0 + c + 1 < N) v1 = p[n0 + c + 1];
    if (n0 + c + 2 < N) v2 = p[n0 + c + 2];
  }
  T[r][c] = v0; T[r][c + 1] = v1; T[r][c + 2] = v2; T[r][c + 3] = v3;
  __syncthreads();
  const int nl = tid >> 3, kl = (tid & 7) * 4;
  const int n = n0 + nl;
  if (n < Npad) {
    short4_t o;
    o.x = (n < N) ? f2bf(T[kl + 0][nl]) : (short)0;
    o.y = (n < N) ? f2bf(T[kl + 1][nl]) : (short)0;
    o.z = (n < N) ? f2bf(T[kl + 2][nl]) : (short)0;
    o.w = (n < N) ? f2bf(T[kl + 3][nl]) : (short)0;
    *(short4_t*)&BT[(size_t)n * K + k0 + kl] = o;
  }
}

// ---------------------------------------------------------------------------
// Shared MFMA machinery: 128x128 tile, BK=64, XOR-swizzled LDS chunk layout.
// LDS slot(row, kc) = row*8 + (kc ^ (row&7)), chunk = 8 shorts (16 B).
// Write side stays contiguous (global_load_lds: uniform base + lane*16B);
// read side (ds_read_b128) becomes 2-way (free) instead of 8-way conflicts.
// ---------------------------------------------------------------------------
__device__ __forceinline__ void stage_tile(const short* __restrict__ G, short* S,
                                           int ld, int base_row, int kt,
                                           int w, int lane) {
  const int rsub = lane >> 3;            // 0..7
  const int kc = (lane & 7) ^ rsub;      // swizzled chunk column
#pragma unroll
  for (int i = 0; i < 4; ++i) {
    const int row = w * 32 + i * 8;
    const short* g = G + (size_t)(base_row + row + rsub) * ld + kt + kc * 8;
    __builtin_amdgcn_global_load_lds(
        (const __attribute__((address_space(1))) void*)g,
        (__attribute__((address_space(3))) void*)(S + row * 64), 16, 0, 0);
  }
}

__device__ __forceinline__ void mfma_mainloop(const short* __restrict__ A,
                                              const short* __restrict__ BT,
                                              short* As, short* Bs,
                                              f32x4 acc[4][4],
                                              int K, int r0, int c0,
                                              int w, int lane) {
  const int quad = lane >> 4, ln = lane & 15;
  const int wm = w >> 1, wn = w & 1;
  const int l7 = ln & 7;
  for (int kt = 0; kt < K; kt += 64) {
    stage_tile(A, As, K, r0, kt, w, lane);
    stage_tile(BT, Bs, K, c0, kt, w, lane);
    __syncthreads();
#pragma unroll
    for (int ks = 0; ks < 2; ++ks) {
      const int kcs = ks * 4 + quad;
      short8 af[4], bfr[4];
#pragma unroll
      for (int mt = 0; mt < 4; ++mt) {
        const int row = wm * 64 + mt * 16 + ln;
        af[mt] = *(const short8*)(As + ((row * 8 + (kcs ^ l7)) << 3));
      }
#pragma unroll
      for (int nt = 0; nt < 4; ++nt) {
        const int rowb = wn * 64 + nt * 16 + ln;
        bfr[nt] = *(const short8*)(Bs + ((rowb * 8 + (kcs ^ l7)) << 3));
      }
#pragma unroll
      for (int mt = 0; mt < 4; ++mt)
#pragma unroll
        for (int nt = 0; nt < 4; ++nt)
          acc[mt][nt] = __builtin_amdgcn_mfma_f32_16x16x32_bf16(
              af[mt], bfr[nt], acc[mt][nt], 0, 0, 0);
    }
    __syncthreads();
  }
}

// C/D layout: col = lane&15, row = (lane>>4)*4 + reg   [verified m89/m91]

// Projection GEMM -> bf16 output only.
__global__ __launch_bounds__(256) void proj_mfma(const short* __restrict__ A,
                                                 const short* __restrict__ BT,
                                                 short* __restrict__ Cb,
                                                 int K, int N) {
  __shared__ short As[128 * 64];
  __shared__ short Bs[128 * 64];
  const int tid = threadIdx.x;
  const int w = tid >> 6, lane = tid & 63;
  const int quad = lane >> 4, ln = lane & 15;
  const int wm = w >> 1, wn = w & 1;
  const int r0 = blockIdx.y * 128, c0 = blockIdx.x * 128;
  f32x4 acc[4][4];
  const f32x4 zero = {0.f, 0.f, 0.f, 0.f};
#pragma unroll
  for (int i = 0; i < 4; ++i)
#pragma unroll
    for (int j = 0; j < 4; ++j) acc[i][j] = zero;
  mfma_mainloop(A, BT, As, Bs, acc, K, r0, c0, w, lane);
#pragma unroll
  for (int mt = 0; mt < 4; ++mt)
#pragma unroll
    for (int r = 0; r < 4; ++r) {
      const int grow = r0 + wm * 64 + mt * 16 + quad * 4 + r;
#pragma unroll
      for (int nt = 0; nt < 4; ++nt) {
        const int cg = c0 + wn * 64 + nt * 16 + ln;
        if (cg < N) Cb[(size_t)grow * N + cg] = f2bf(acc[mt][nt][r]);
      }
    }
}

// Fused logits GEMM + per-(row, 128-col-tile) sum-of-exp partials (no max:
// logits here are O(1); exp is safe in fp32). blockIdx.x = row-block with
// device-count early exit; blockIdx.y = col-split (B-tile L2 reuse per XCD).
__global__ __launch_bounds__(256) void logit_mfma(const short* __restrict__ A,
                                                  const short* __restrict__ BT,
                                                  const float* __restrict__ bias,
                                                  float* __restrict__ ps,
                                                  const int* __restrict__ cntp,
                                                  int cidx, int K, int Ncols) {
  const int r0 = blockIdx.x * 128;
  if (r0 >= cntp[cidx]) return;
  __shared__ short As[128 * 64];
  __shared__ short Bs[128 * 64];
  __shared__ float psL[2][128];
  const int tid = threadIdx.x;
  const int w = tid >> 6, lane = tid & 63;
  const int quad = lane >> 4, ln = lane & 15;
  const int wm = w >> 1, wn = w & 1;
  const int c0 = blockIdx.y * 128;
  const int nsplit = gridDim.y;
  f32x4 acc[4][4];
  const f32x4 zero = {0.f, 0.f, 0.f, 0.f};
#pragma unroll
  for (int i = 0; i < 4; ++i)
#pragma unroll
    for (int j = 0; j < 4; ++j) acc[i][j] = zero;
  mfma_mainloop(A, BT, As, Bs, acc, K, r0, c0, w, lane);

  // preload bias + validity once (4 regs each)
  float bv[4], vm[4];
#pragma unroll
  for (int nt = 0; nt < 4; ++nt) {
    const int cg = c0 + wn * 64 + nt * 16 + ln;
    vm[nt] = (cg < Ncols) ? 1.f : 0.f;
    bv[nt] = (cg < Ncols) ? bias[cg] : 0.f;
  }
#pragma unroll
  for (int mt = 0; mt < 4; ++mt)
#pragma unroll
    for (int r = 0; r < 4; ++r) {
      float s = 0.f;
#pragma unroll
      for (int nt = 0; nt < 4; ++nt)
        s += vm[nt] * __expf(acc[mt][nt][r] + bv[nt]);
#pragma unroll
      for (int off = 1; off < 16; off <<= 1) s += __shfl_xor(s, off, 64);
      if (ln == 0) psL[wn][wm * 64 + mt * 16 + quad * 4 + r] = s;
    }
  __syncthreads();
  if (tid < 128)
    ps[(size_t)(r0 + tid) * nsplit + blockIdx.y] = psL[0][tid] + psL[1][tid];
}

// ---------------------------------------------------------------------------
// Gather tail rows into compacted A buffers (zeros for pad slots).
// blocks 0..511: tail1 (4 slots/blk, K=256); 512..639: tail2 (16 slots/blk, K=64)
// ---------------------------------------------------------------------------
__global__ __launch_bounds__(256) void gather_tails(const short* __restrict__ P1b,
                                                    const short* __restrict__ P2b,
                                                    short* __restrict__ A1c,
                                                    short* __restrict__ A2c,
                                                    const int* __restrict__ rows1,
                                                    const int* __restrict__ rows2,
                                                    const int* __restrict__ counts) {
  int b = blockIdx.x;
  const int lane = threadIdx.x & 63, wv = threadIdx.x >> 6;
  if (b < 512) {
    const int slot = b * 4 + wv;
    const int c1 = counts[1];
    short4_t v = {0, 0, 0, 0};
    if (slot < c1) v = *(const short4_t*)(P1b + (size_t)rows1[slot] * 256 + lane * 4);
    *(short4_t*)(A1c + (size_t)slot * 256 + lane * 4) = v;
  } else {
    b -= 512;
    const int slot = b * 16 + wv * 4 + (lane >> 4);
    const int c2 = counts[2];
    const int l16 = lane & 15;
    short4_t v = {0, 0, 0, 0};
    if (slot < c2) v = *(const short4_t*)(P2b + (size_t)rows2[slot] * 64 + l16 * 4);
    *(short4_t*)(A2c + (size_t)slot * 64 + l16 * 4) = v;
  }
}

// ---------------------------------------------------------------------------
// Finalize: one wave per row. Partials are plain sum-of-exp; lse = log(S).
// ---------------------------------------------------------------------------
__device__ __forceinline__ float wave_sum(float a) {
#pragma unroll
  for (int off = 32; off; off >>= 1) a += __shfl_xor(a, off, 64);
  return a;
}

__global__ __launch_bounds__(256) void finalize(
    const short* __restrict__ P0b, const short* __restrict__ P1b,
    const short* __restrict__ P2b,
    const float* __restrict__ Wl0, const float* __restrict__ bl0,
    const float* __restrict__ Wl1, const float* __restrict__ bl1,
    const float* __restrict__ Wl2, const float* __restrict__ bl2,
    const float* __restrict__ Wc, const float* __restrict__ bc,
    const int* __restrict__ y, const int* __restrict__ slot_of_row,
    const float* __restrict__ psh, int nsh,
    const float* __restrict__ ps1, int ns1,
    const float* __restrict__ ps2, int ns2,
    float* __restrict__ out) {
  const int lane = threadIdx.x & 63;
  const int row = blockIdx.x * 4 + (threadIdx.x >> 6);

  float a0 = 0.f, a1 = 0.f;
  for (int k = lane; k < HID; k += 64) {
    const float p = bf2f(P0b[(size_t)row * HID + k]);
    a0 += p * Wc[2 * k];
    a1 += p * Wc[2 * k + 1];
  }
  a0 = wave_sum(a0);
  a1 = wave_sum(a1);
  const float cl0 = a0 + bc[0], cl1 = a1 + bc[1];

  float S = 0.f;
  for (int i = lane; i < nsh; i += 64) S += psh[(size_t)row * nsh + i];
  S = wave_sum(S) + __expf(cl0) + __expf(cl1);
  const float lse = logf(S);

  const int yy = y[row];
  float nll;
  if (yy < 10000) {
    float a = 0.f;
    for (int k = lane; k < HID; k += 64)
      a += bf2f(P0b[(size_t)row * HID + k]) * Wl0[(size_t)k * 10000 + yy];
    a = wave_sum(a);
    nll = -((a + bl0[yy]) - lse);
  } else if (yy < 20000) {
    const int t = yy - 10000;
    const int slot = slot_of_row[row];
    float S1 = 0.f;
    for (int i = lane; i < ns1; i += 64) S1 += ps1[(size_t)slot * ns1 + i];
    S1 = wave_sum(S1);
    const float lse1 = logf(S1);
    float a = 0.f;
    for (int k = lane; k < 256; k += 64)
      a += bf2f(P1b[(size_t)row * 256 + k]) * Wl1[(size_t)k * 30000 + t];
    a = wave_sum(a);
    nll = -((cl1 - lse) + ((a + bl1[t]) - lse1));
  } else {
    const int t = yy - 20000;
    const int slot = slot_of_row[row];
    float S2 = 0.f;
    for (int i = lane; i < ns2; i += 64) S2 += ps2[(size_t)slot * ns2 + i];
    S2 = wave_sum(S2);
    const float lse2 = logf(S2);
    float a = 0.f;
    for (int k = lane; k < 64; k += 64)
      a += bf2f(P2b[(size_t)row * 64 + k]) * Wl2[(size_t)k * 52000 + t];
    a = wave_sum(a);
    nll = -((cl0 - lse) + ((a + bl2[t]) - lse2));
  }
  if (lane == 0) out[row] = nll;
}

// ---------------------------------------------------------------------------
extern "C" void kernel_launch(void* const* d_in, const int* in_sizes, int n_in,
                              void* d_out, int out_size, void* d_ws, size_t ws_size,
                              hipStream_t stream) {
  const float* x   = (const float*)d_in[0];
  const int*   y   = (const int*)d_in[1];
  const float* Wp0 = (const float*)d_in[2];
  const float* Wp1 = (const float*)d_in[3];
  const float* Wp2 = (const float*)d_in[4];
  const float* Wl0 = (const float*)d_in[5];
  const float* bl0 = (const float*)d_in[6];
  const float* Wl1 = (const float*)d_in[7];
  const float* bl1 = (const float*)d_in[8];
  const float* Wl2 = (const float*)d_in[9];
  const float* bl2 = (const float*)d_in[10];
  const float* Wc  = (const float*)d_in[11];
  const float* bc  = (const float*)d_in[12];
  float* out = (float*)d_out;

  const int nsh = 79;   // ceil(10000/128)
  const int ns1 = 235;  // ceil(30000/128)
  const int ns2 = 407;  // ceil(52000/128)

  float* fws = (float*)d_ws;
  float* psh = fws; fws += (size_t)NROWS * nsh;
  float* ps1 = fws; fws += (size_t)NROWS * ns1;
  float* ps2 = fws; fws += (size_t)NROWS * ns2;
  int* iws = (int*)fws;
  int* counts       = iws; iws += 4;
  int* slot_of_row  = iws; iws += NROWS;
  int* rows1        = iws; iws += NROWS;
  int* rows2        = iws; iws += NROWS;
  short* sp = (short*)iws;
  short* xb   = sp; sp += (size_t)NROWS * 1024;
  short* P0b  = sp; sp += (size_t)NROWS * 1024;
  short* P1b  = sp; sp += (size_t)NROWS * 256;
  short* P2b  = sp; sp += (size_t)NROWS * 64;
  short* A1c  = sp; sp += (size_t)NROWS * 256;
  short* A2c  = sp; sp += (size_t)NROWS * 64;
  short* WpT0 = sp; sp += (size_t)1024 * 1024;
  short* WpT1 = sp; sp += (size_t)256 * 1024;
  short* WpT2 = sp; sp += (size_t)128 * 1024;
  short* WlT0 = sp; sp += (size_t)10112 * 1024;
  short* WlT1 = sp; sp += (size_t)30080 * 256;
  short* WlT2 = sp; sp += (size_t)52096 * 64;

  dim3 blk(256);
  classify<<<dim3(1), dim3(1024), 0, stream>>>(y, counts, slot_of_row, rows1, rows2);
  cvt_bf16<<<dim3((NROWS * 1024) / 1024), blk, 0, stream>>>(x, xb);
  transpose_all<<<dim3(22296), blk, 0, stream>>>(Wp0, Wp1, Wp2, Wl0, Wl1, Wl2,
                                                 WpT0, WpT1, WpT2, WlT0, WlT1, WlT2);
  // projections (all rows; finalize needs per-row P for target dots)
  proj_mfma<<<dim3(8, NROWS / 128), blk, 0, stream>>>(xb, WpT0, P0b, 1024, 1024);
  proj_mfma<<<dim3(2, NROWS / 128), blk, 0, stream>>>(xb, WpT1, P1b, 1024, 256);
  proj_mfma<<<dim3(1, NROWS / 128), blk, 0, stream>>>(xb, WpT2, P2b, 1024, 64);
  // compact tail rows
  gather_tails<<<dim3(640), blk, 0, stream>>>(P1b, P2b, A1c, A2c, rows1, rows2, counts);
  // fused logits + sum-of-exp partials
  logit_mfma<<<dim3(NROWS / 128, nsh), blk, 0, stream>>>(P0b, WlT0, bl0, psh, counts, 0, 1024, 10000);
  logit_mfma<<<dim3(NROWS / 128, ns1), blk, 0, stream>>>(A1c, WlT1, bl1, ps1, counts, 1, 256, 30000);
  logit_mfma<<<dim3(NROWS / 128, ns2), blk, 0, stream>>>(A2c, WlT2, bl2, ps2, counts, 2, 64, 52000);
  // merge + target logits + nll
  finalize<<<dim3(NROWS / 4), blk, 0, stream>>>(P0b, P1b, P2b, Wl0, bl0, Wl1, bl1,
                                                Wl2, bl2, Wc, bc, y, slot_of_row,
                                                psh, nsh, ps1, ns1, ps2, ns2, out);
}

// Round 4
// 318.867 us; speedup vs baseline: 6.1444x; 1.3303x over previous
//
#include <hip/hip_runtime.h>
#include <math.h>

#define HID 1024
#define NROWS 2048

typedef __attribute__((ext_vector_type(8))) short short8;
typedef __attribute__((ext_vector_type(4))) short short4_t;
typedef __attribute__((ext_vector_type(4))) float f32x4;

__device__ __forceinline__ short f2bf(float f) {
  union { float f; unsigned u; } v; v.f = f;
  unsigned r = v.u + 0x7fffu + ((v.u >> 16) & 1u);
  return (short)(r >> 16);
}
__device__ __forceinline__ float bf2f(short s) {
  union { unsigned u; float f; } v; v.u = ((unsigned)(unsigned short)s) << 16;
  return v.f;
}
__device__ __forceinline__ float wave_sum(float a) {
#pragma unroll
  for (int off = 32; off; off >>= 1) a += __shfl_xor(a, off, 64);
  return a;
}

// ---------------------------------------------------------------------------
// PREP (one launch): block 0 = classify; blocks 1..2048 = x fp32->bf16;
// blocks 2049.. = all six weight transposes (fp32 [K,N] -> bf16 [Npad,K]).
// Transpose block counts: 1024, 256, 128, 10112, 7520, 3256  (= 22296).
// Total grid = 1 + 2048 + 22296 = 24345.
// ---------------------------------------------------------------------------
__global__ __launch_bounds__(256) void prep(
    const float* __restrict__ x, const int* __restrict__ y,
    const float* __restrict__ Wp0, const float* __restrict__ Wp1,
    const float* __restrict__ Wp2, const float* __restrict__ Wl0,
    const float* __restrict__ Wl1, const float* __restrict__ Wl2,
    short* __restrict__ xb,
    int* __restrict__ counts, int* __restrict__ slot_of_row,
    int* __restrict__ rows1, int* __restrict__ rows2,
    short* __restrict__ T0, short* __restrict__ T1, short* __restrict__ T2,
    short* __restrict__ T3, short* __restrict__ T4, short* __restrict__ T5) {
  const int tid = threadIdx.x;
  int b = blockIdx.x;
  if (b == 0) {                       // ---- classify ----
    __shared__ int c1s, c2s;
    if (tid == 0) { c1s = 0; c2s = 0; }
    __syncthreads();
    for (int r = tid; r < NROWS; r += 256) {
      const int yy = y[r];
      if (yy >= 20000) {
        const int s = atomicAdd(&c2s, 1);
        slot_of_row[r] = s; rows2[s] = r;
      } else if (yy >= 10000) {
        const int s = atomicAdd(&c1s, 1);
        slot_of_row[r] = s; rows1[s] = r;
      } else {
        slot_of_row[r] = -1;
      }
    }
    __syncthreads();
    if (tid == 0) { counts[0] = NROWS; counts[1] = c1s; counts[2] = c2s; }
    return;
  }
  if (b <= 2048) {                    // ---- cvt x ----
    const int i = ((b - 1) * 256 + tid) * 4;
    short4_t o;
    o.x = f2bf(x[i + 0]); o.y = f2bf(x[i + 1]);
    o.z = f2bf(x[i + 2]); o.w = f2bf(x[i + 3]);
    *(short4_t*)&xb[i] = o;
    return;
  }
  b -= 2049;                          // ---- transposes ----
  const float* W; short* BT; int K, N, Npad, tn;
  if (b < 1024)                { W = Wp0; BT = T0; K = 1024; N = 1024;  Npad = 1024;  tn = 32;   }
  else if ((b -= 1024) < 256)  { W = Wp1; BT = T1; K = 1024; N = 256;   Npad = 256;   tn = 8;    }
  else if ((b -= 256) < 128)   { W = Wp2; BT = T2; K = 1024; N = 64;    Npad = 128;   tn = 4;    }
  else if ((b -= 128) < 10112) { W = Wl0; BT = T3; K = 1024; N = 10000; Npad = 10112; tn = 316;  }
  else if ((b -= 10112) < 7520){ W = Wl1; BT = T4; K = 256;  N = 30000; Npad = 30080; tn = 940;  }
  else { b -= 7520;              W = Wl2; BT = T5; K = 64;   N = 52000; Npad = 52096; tn = 1628; }

  __shared__ float T[32][33];
  const int n0 = (b % tn) * 32, k0 = (b / tn) * 32;
  const int r = tid >> 3, c = (tid & 7) * 4;
  float v0 = 0.f, v1 = 0.f, v2 = 0.f, v3 = 0.f;
  const float* p = &W[(size_t)(k0 + r) * N];
  if (n0 + c + 3 < N) {
    v0 = p[n0 + c]; v1 = p[n0 + c + 1]; v2 = p[n0 + c + 2]; v3 = p[n0 + c + 3];
  } else {
    if (n0 + c + 0 < N) v0 = p[n0 + c + 0];
    if (n0 + c + 1 < N) v1 = p[n0 + c + 1];
    if (n0 + c + 2 < N) v2 = p[n0 + c + 2];
  }
  T[r][c] = v0; T[r][c + 1] = v1; T[r][c + 2] = v2; T[r][c + 3] = v3;
  __syncthreads();
  const int nl = tid >> 3, kl = (tid & 7) * 4;
  const int n = n0 + nl;
  if (n < Npad) {
    short4_t o;
    o.x = (n < N) ? f2bf(T[kl + 0][nl]) : (short)0;
    o.y = (n < N) ? f2bf(T[kl + 1][nl]) : (short)0;
    o.z = (n < N) ? f2bf(T[kl + 2][nl]) : (short)0;
    o.w = (n < N) ? f2bf(T[kl + 3][nl]) : (short)0;
    *(short4_t*)&BT[(size_t)n * K + k0 + kl] = o;
  }
}

// ---------------------------------------------------------------------------
// MFMA main loop: 128x128 tile, BK=64, XOR-swizzled LDS (verified 0 conflicts).
// Per-lane global base pointers precomputed by caller (enables row gather).
// ---------------------------------------------------------------------------
__device__ __forceinline__ void mfma_mainloop(const short* aB[4], const short* bB[4],
                                              short* As, short* Bs,
                                              f32x4 acc[4][4],
                                              int K, int w, int lane) {
  const int quad = lane >> 4, ln = lane & 15;
  const int wm = w >> 1, wn = w & 1;
  const int l7 = ln & 7;
  for (int kt = 0; kt < K; kt += 64) {
#pragma unroll
    for (int i = 0; i < 4; ++i) {
      const int row = w * 32 + i * 8;
      __builtin_amdgcn_global_load_lds(
          (const __attribute__((address_space(1))) void*)(aB[i] + kt),
          (__attribute__((address_space(3))) void*)(As + row * 64), 16, 0, 0);
      __builtin_amdgcn_global_load_lds(
          (const __attribute__((address_space(1))) void*)(bB[i] + kt),
          (__attribute__((address_space(3))) void*)(Bs + row * 64), 16, 0, 0);
    }
    __syncthreads();
#pragma unroll
    for (int ks = 0; ks < 2; ++ks) {
      const int kcs = ks * 4 + quad;
      short8 af[4], bfr[4];
#pragma unroll
      for (int mt = 0; mt < 4; ++mt) {
        const int row = wm * 64 + mt * 16 + ln;
        af[mt] = *(const short8*)(As + ((row * 8 + (kcs ^ l7)) << 3));
      }
#pragma unroll
      for (int nt = 0; nt < 4; ++nt) {
        const int rowb = wn * 64 + nt * 16 + ln;
        bfr[nt] = *(const short8*)(Bs + ((rowb * 8 + (kcs ^ l7)) << 3));
      }
#pragma unroll
      for (int mt = 0; mt < 4; ++mt)
#pragma unroll
        for (int nt = 0; nt < 4; ++nt)
          acc[mt][nt] = __builtin_amdgcn_mfma_f32_16x16x32_bf16(
              af[mt], bfr[nt], acc[mt][nt], 0, 0, 0);
    }
    __syncthreads();
  }
}

// C/D layout: col = lane&15, row = (lane>>4)*4 + reg   [verified m89/m91]

// ---------------------------------------------------------------------------
// PROJ_ALL (one launch, 176 blocks): head proj (128 blocks, all rows) +
// tail1 proj on compacted rows (32 blocks, inline gather via rows1) +
// tail2 proj on compacted rows (16 blocks, via rows2).
// ---------------------------------------------------------------------------
__global__ __launch_bounds__(256) void proj_all(
    const short* __restrict__ xb,
    const short* __restrict__ WpT0, const short* __restrict__ WpT1,
    const short* __restrict__ WpT2,
    short* __restrict__ P0b, short* __restrict__ P1c, short* __restrict__ P2c,
    const int* __restrict__ rows1, const int* __restrict__ rows2,
    const int* __restrict__ counts) {
  int b = blockIdx.x;
  const short* BT; short* C; int N, r0, c0, cnt;
  const int* rowlist = nullptr;
  if (b < 128) {
    BT = WpT0; C = P0b; N = 1024;
    c0 = (b & 7) * 128; r0 = (b >> 3) * 128; cnt = NROWS;
  } else if (b < 160) {
    b -= 128; BT = WpT1; C = P1c; N = 256;
    c0 = (b & 1) * 128; r0 = (b >> 1) * 128; rowlist = rows1; cnt = counts[1];
  } else {
    b -= 160; BT = WpT2; C = P2c; N = 64;
    c0 = 0; r0 = b * 128; rowlist = rows2; cnt = counts[2];
  }
  if (r0 >= cnt) return;

  __shared__ short As[128 * 64];
  __shared__ short Bs[128 * 64];
  const int tid = threadIdx.x;
  const int w = tid >> 6, lane = tid & 63;
  const int quad = lane >> 4, ln = lane & 15;
  const int wm = w >> 1, wn = w & 1;
  const int rsub = lane >> 3;
  const int kc = (lane & 7) ^ rsub;
  const int K = 1024;

  const short* aB[4]; const short* bB[4];
#pragma unroll
  for (int i = 0; i < 4; ++i) {
    const int sl = r0 + w * 32 + i * 8 + rsub;
    const int ar = rowlist ? rowlist[sl < cnt ? sl : cnt - 1] : sl;
    aB[i] = xb + (size_t)ar * K + kc * 8;
    bB[i] = BT + (size_t)(c0 + w * 32 + i * 8 + rsub) * K + kc * 8;
  }

  f32x4 acc[4][4];
  const f32x4 zero = {0.f, 0.f, 0.f, 0.f};
#pragma unroll
  for (int i = 0; i < 4; ++i)
#pragma unroll
    for (int j = 0; j < 4; ++j) acc[i][j] = zero;
  mfma_mainloop(aB, bB, As, Bs, acc, K, w, lane);
#pragma unroll
  for (int mt = 0; mt < 4; ++mt)
#pragma unroll
    for (int r = 0; r < 4; ++r) {
      const int grow = r0 + wm * 64 + mt * 16 + quad * 4 + r;
#pragma unroll
      for (int nt = 0; nt < 4; ++nt) {
        const int cg = c0 + wn * 64 + nt * 16 + ln;
        if (cg < N) C[(size_t)grow * N + cg] = f2bf(acc[mt][nt][r]);
      }
    }
}

// ---------------------------------------------------------------------------
// LOGIT_ALL (one launch): head (16x79=1264 blocks, first) + tail1 (16x235)
// + tail2 (16x407), tails early-exit past their compacted row count.
// Emits per-(row, 128-col-split) sum-of-exp partials.
// ---------------------------------------------------------------------------
#define HB  (16 * 79)
#define T1B (16 * 235)
#define T2B (16 * 407)

__global__ __launch_bounds__(256) void logit_all(
    const short* __restrict__ P0b, const short* __restrict__ WlT0,
    const float* __restrict__ bl0, float* __restrict__ psh,
    const short* __restrict__ P1c, const short* __restrict__ WlT1,
    const float* __restrict__ bl1, float* __restrict__ ps1,
    const short* __restrict__ P2c, const short* __restrict__ WlT2,
    const float* __restrict__ bl2, float* __restrict__ ps2,
    const int* __restrict__ counts) {
  int b = blockIdx.x;
  const short* A; const short* BT; const float* bias; float* ps;
  int K, Ncols, nsplit, rb, cs, cnt;
  if (b < HB) {
    A = P0b; BT = WlT0; bias = bl0; ps = psh;
    K = 1024; Ncols = 10000; nsplit = 79; rb = b / 79; cs = b % 79; cnt = NROWS;
  } else if ((b -= HB) < T1B) {
    A = P1c; BT = WlT1; bias = bl1; ps = ps1;
    K = 256; Ncols = 30000; nsplit = 235; rb = b / 235; cs = b % 235; cnt = counts[1];
  } else {
    b -= T1B;
    A = P2c; BT = WlT2; bias = bl2; ps = ps2;
    K = 64; Ncols = 52000; nsplit = 407; rb = b / 407; cs = b % 407; cnt = counts[2];
  }
  const int r0 = rb * 128, c0 = cs * 128;
  if (r0 >= cnt) return;

  __shared__ short As[128 * 64];
  __shared__ short Bs[128 * 64];
  __shared__ float psL[2][128];
  const int tid = threadIdx.x;
  const int w = tid >> 6, lane = tid & 63;
  const int quad = lane >> 4, ln = lane & 15;
  const int wm = w >> 1, wn = w & 1;
  const int rsub = lane >> 3;
  const int kc = (lane & 7) ^ rsub;

  const short* aB[4]; const short* bB[4];
#pragma unroll
  for (int i = 0; i < 4; ++i) {
    aB[i] = A + (size_t)(r0 + w * 32 + i * 8 + rsub) * K + kc * 8;
    bB[i] = BT + (size_t)(c0 + w * 32 + i * 8 + rsub) * K + kc * 8;
  }

  f32x4 acc[4][4];
  const f32x4 zero = {0.f, 0.f, 0.f, 0.f};
#pragma unroll
  for (int i = 0; i < 4; ++i)
#pragma unroll
    for (int j = 0; j < 4; ++j) acc[i][j] = zero;
  mfma_mainloop(aB, bB, As, Bs, acc, K, w, lane);

  float bv[4], vm[4];
#pragma unroll
  for (int nt = 0; nt < 4; ++nt) {
    const int cg = c0 + wn * 64 + nt * 16 + ln;
    vm[nt] = (cg < Ncols) ? 1.f : 0.f;
    bv[nt] = (cg < Ncols) ? bias[cg] : 0.f;
  }
#pragma unroll
  for (int mt = 0; mt < 4; ++mt)
#pragma unroll
    for (int r = 0; r < 4; ++r) {
      float s = 0.f;
#pragma unroll
      for (int nt = 0; nt < 4; ++nt)
        s += vm[nt] * __expf(acc[mt][nt][r] + bv[nt]);
#pragma unroll
      for (int off = 1; off < 16; off <<= 1) s += __shfl_xor(s, off, 64);
      if (ln == 0) psL[wn][wm * 64 + mt * 16 + quad * 4 + r] = s;
    }
  __syncthreads();
  if (tid < 128)
    ps[(size_t)(r0 + tid) * nsplit + cs] = psL[0][tid] + psL[1][tid];
}

// ---------------------------------------------------------------------------
// FINALIZE: one wave per row. Target dots use the bf16 transposed weights
// (contiguous rows) instead of strided fp32 columns.
// ---------------------------------------------------------------------------
__global__ __launch_bounds__(256) void finalize(
    const short* __restrict__ P0b, const short* __restrict__ P1c,
    const short* __restrict__ P2c,
    const short* __restrict__ WlT0, const float* __restrict__ bl0,
    const short* __restrict__ WlT1, const float* __restrict__ bl1,
    const short* __restrict__ WlT2, const float* __restrict__ bl2,
    const float* __restrict__ Wc, const float* __restrict__ bc,
    const int* __restrict__ y, const int* __restrict__ slot_of_row,
    const float* __restrict__ psh, const float* __restrict__ ps1,
    const float* __restrict__ ps2, float* __restrict__ out) {
  const int lane = threadIdx.x & 63;
  const int row = blockIdx.x * 4 + (threadIdx.x >> 6);

  float a0 = 0.f, a1 = 0.f;
  for (int k = lane; k < HID; k += 64) {
    const float p = bf2f(P0b[(size_t)row * HID + k]);
    a0 += p * Wc[2 * k];
    a1 += p * Wc[2 * k + 1];
  }
  a0 = wave_sum(a0);
  a1 = wave_sum(a1);
  const float cl0 = a0 + bc[0], cl1 = a1 + bc[1];

  float S = 0.f;
  for (int i = lane; i < 79; i += 64) S += psh[(size_t)row * 79 + i];
  S = wave_sum(S) + __expf(cl0) + __expf(cl1);
  const float lse = logf(S);

  const int yy = y[row];
  float nll;
  if (yy < 10000) {
    const short* pr = P0b + (size_t)row * 1024;
    const short* wr = WlT0 + (size_t)yy * 1024;
    float a = 0.f;
    for (int kk = lane * 4; kk < 1024; kk += 256) {
      const short4_t p = *(const short4_t*)(pr + kk);
      const short4_t wv = *(const short4_t*)(wr + kk);
      a += bf2f(p.x) * bf2f(wv.x) + bf2f(p.y) * bf2f(wv.y)
         + bf2f(p.z) * bf2f(wv.z) + bf2f(p.w) * bf2f(wv.w);
    }
    a = wave_sum(a);
    nll = -((a + bl0[yy]) - lse);
  } else if (yy < 20000) {
    const int t = yy - 10000;
    const int slot = slot_of_row[row];
    float S1 = 0.f;
    for (int i = lane; i < 235; i += 64) S1 += ps1[(size_t)slot * 235 + i];
    S1 = wave_sum(S1);
    const short* pr = P1c + (size_t)slot * 256;
    const short* wr = WlT1 + (size_t)t * 256;
    const int kk = lane * 4;
    const short4_t p = *(const short4_t*)(pr + kk);
    const short4_t wv = *(const short4_t*)(wr + kk);
    float a = bf2f(p.x) * bf2f(wv.x) + bf2f(p.y) * bf2f(wv.y)
            + bf2f(p.z) * bf2f(wv.z) + bf2f(p.w) * bf2f(wv.w);
    a = wave_sum(a);
    nll = -((cl1 - lse) + ((a + bl1[t]) - logf(S1)));
  } else {
    const int t = yy - 20000;
    const int slot = slot_of_row[row];
    float S2 = 0.f;
    for (int i = lane; i < 407; i += 64) S2 += ps2[(size_t)slot * 407 + i];
    S2 = wave_sum(S2);
    float a = 0.f;
    if (lane < 16) {
      const short* pr = P2c + (size_t)slot * 64;
      const short* wr = WlT2 + (size_t)t * 64;
      const int kk = lane * 4;
      const short4_t p = *(const short4_t*)(pr + kk);
      const short4_t wv = *(const short4_t*)(wr + kk);
      a = bf2f(p.x) * bf2f(wv.x) + bf2f(p.y) * bf2f(wv.y)
        + bf2f(p.z) * bf2f(wv.z) + bf2f(p.w) * bf2f(wv.w);
    }
    a = wave_sum(a);
    nll = -((cl0 - lse) + ((a + bl2[t]) - logf(S2)));
  }
  if (lane == 0) out[row] = nll;
}

// ---------------------------------------------------------------------------
extern "C" void kernel_launch(void* const* d_in, const int* in_sizes, int n_in,
                              void* d_out, int out_size, void* d_ws, size_t ws_size,
                              hipStream_t stream) {
  const float* x   = (const float*)d_in[0];
  const int*   y   = (const int*)d_in[1];
  const float* Wp0 = (const float*)d_in[2];
  const float* Wp1 = (const float*)d_in[3];
  const float* Wp2 = (const float*)d_in[4];
  const float* Wl0 = (const float*)d_in[5];
  const float* bl0 = (const float*)d_in[6];
  const float* Wl1 = (const float*)d_in[7];
  const float* bl1 = (const float*)d_in[8];
  const float* Wl2 = (const float*)d_in[9];
  const float* bl2 = (const float*)d_in[10];
  const float* Wc  = (const float*)d_in[11];
  const float* bc  = (const float*)d_in[12];
  float* out = (float*)d_out;

  float* fws = (float*)d_ws;
  float* psh = fws; fws += (size_t)NROWS * 79;
  float* ps1 = fws; fws += (size_t)NROWS * 235;
  float* ps2 = fws; fws += (size_t)NROWS * 407;
  int* iws = (int*)fws;
  int* counts      = iws; iws += 4;
  int* slot_of_row = iws; iws += NROWS;
  int* rows1       = iws; iws += NROWS;
  int* rows2       = iws; iws += NROWS;
  short* sp = (short*)iws;
  short* xb   = sp; sp += (size_t)NROWS * 1024;
  short* P0b  = sp; sp += (size_t)NROWS * 1024;
  short* P1c  = sp; sp += (size_t)NROWS * 256;
  short* P2c  = sp; sp += (size_t)NROWS * 64;
  short* WpT0 = sp; sp += (size_t)1024 * 1024;
  short* WpT1 = sp; sp += (size_t)256 * 1024;
  short* WpT2 = sp; sp += (size_t)128 * 1024;
  short* WlT0 = sp; sp += (size_t)10112 * 1024;
  short* WlT1 = sp; sp += (size_t)30080 * 256;
  short* WlT2 = sp; sp += (size_t)52096 * 64;

  dim3 blk(256);
  prep<<<dim3(24345), blk, 0, stream>>>(x, y, Wp0, Wp1, Wp2, Wl0, Wl1, Wl2,
                                        xb, counts, slot_of_row, rows1, rows2,
                                        WpT0, WpT1, WpT2, WlT0, WlT1, WlT2);
  proj_all<<<dim3(176), blk, 0, stream>>>(xb, WpT0, WpT1, WpT2, P0b, P1c, P2c,
                                          rows1, rows2, counts);
  logit_all<<<dim3(HB + T1B + T2B), blk, 0, stream>>>(
      P0b, WlT0, bl0, psh, P1c, WlT1, bl1, ps1, P2c, WlT2, bl2, ps2, counts);
  finalize<<<dim3(NROWS / 4), blk, 0, stream>>>(
      P0b, P1c, P2c, WlT0, bl0, WlT1, bl1, WlT2, bl2, Wc, bc, y, slot_of_row,
      psh, ps1, ps2, out);
}

// Round 5
// 309.947 us; speedup vs baseline: 6.3212x; 1.0288x over previous
//
#include <hip/hip_runtime.h>
#include <math.h>

#define HID 1024
#define NROWS 2048

typedef __attribute__((ext_vector_type(8))) short short8;
typedef __attribute__((ext_vector_type(4))) short short4_t;
typedef __attribute__((ext_vector_type(4))) float f32x4;

__device__ __forceinline__ short f2bf(float f) {
  union { float f; unsigned u; } v; v.f = f;
  unsigned r = v.u + 0x7fffu + ((v.u >> 16) & 1u);
  return (short)(r >> 16);
}
__device__ __forceinline__ float bf2f(short s) {
  union { unsigned u; float f; } v; v.u = ((unsigned)(unsigned short)s) << 16;
  return v.f;
}
__device__ __forceinline__ float wave_sum(float a) {
#pragma unroll
  for (int off = 32; off; off >>= 1) a += __shfl_xor(a, off, 64);
  return a;
}

// ---------------------------------------------------------------------------
// PREP (one launch): block 0 = classify; blocks 1..2048 = x fp32->bf16;
// blocks 2049.. = all six weight transposes (fp32 [K,N] -> bf16 [Npad,K]).
// Transpose block counts: 1024, 256, 128, 10112, 7520, 3256  (= 22296).
// Total grid = 1 + 2048 + 22296 = 24345.
// ---------------------------------------------------------------------------
__global__ __launch_bounds__(256) void prep(
    const float* __restrict__ x, const int* __restrict__ y,
    const float* __restrict__ Wp0, const float* __restrict__ Wp1,
    const float* __restrict__ Wp2, const float* __restrict__ Wl0,
    const float* __restrict__ Wl1, const float* __restrict__ Wl2,
    short* __restrict__ xb,
    int* __restrict__ counts, int* __restrict__ slot_of_row,
    int* __restrict__ rows1, int* __restrict__ rows2,
    short* __restrict__ T0, short* __restrict__ T1, short* __restrict__ T2,
    short* __restrict__ T3, short* __restrict__ T4, short* __restrict__ T5) {
  const int tid = threadIdx.x;
  int b = blockIdx.x;
  if (b == 0) {                       // ---- classify ----
    __shared__ int c1s, c2s;
    if (tid == 0) { c1s = 0; c2s = 0; }
    __syncthreads();
    for (int r = tid; r < NROWS; r += 256) {
      const int yy = y[r];
      if (yy >= 20000) {
        const int s = atomicAdd(&c2s, 1);
        slot_of_row[r] = s; rows2[s] = r;
      } else if (yy >= 10000) {
        const int s = atomicAdd(&c1s, 1);
        slot_of_row[r] = s; rows1[s] = r;
      } else {
        slot_of_row[r] = -1;
      }
    }
    __syncthreads();
    if (tid == 0) { counts[0] = NROWS; counts[1] = c1s; counts[2] = c2s; }
    return;
  }
  if (b <= 2048) {                    // ---- cvt x ----
    const int i = ((b - 1) * 256 + tid) * 4;
    short4_t o;
    o.x = f2bf(x[i + 0]); o.y = f2bf(x[i + 1]);
    o.z = f2bf(x[i + 2]); o.w = f2bf(x[i + 3]);
    *(short4_t*)&xb[i] = o;
    return;
  }
  b -= 2049;                          // ---- transposes ----
  const float* W; short* BT; int K, N, Npad, tn;
  if (b < 1024)                { W = Wp0; BT = T0; K = 1024; N = 1024;  Npad = 1024;  tn = 32;   }
  else if ((b -= 1024) < 256)  { W = Wp1; BT = T1; K = 1024; N = 256;   Npad = 256;   tn = 8;    }
  else if ((b -= 256) < 128)   { W = Wp2; BT = T2; K = 1024; N = 64;    Npad = 128;   tn = 4;    }
  else if ((b -= 128) < 10112) { W = Wl0; BT = T3; K = 1024; N = 10000; Npad = 10112; tn = 316;  }
  else if ((b -= 10112) < 7520){ W = Wl1; BT = T4; K = 256;  N = 30000; Npad = 30080; tn = 940;  }
  else { b -= 7520;              W = Wl2; BT = T5; K = 64;   N = 52000; Npad = 52096; tn = 1628; }

  __shared__ float T[32][33];
  const int n0 = (b % tn) * 32, k0 = (b / tn) * 32;
  const int r = tid >> 3, c = (tid & 7) * 4;
  float v0 = 0.f, v1 = 0.f, v2 = 0.f, v3 = 0.f;
  const float* p = &W[(size_t)(k0 + r) * N];
  if (n0 + c + 3 < N) {
    v0 = p[n0 + c]; v1 = p[n0 + c + 1]; v2 = p[n0 + c + 2]; v3 = p[n0 + c + 3];
  } else {
    if (n0 + c + 0 < N) v0 = p[n0 + c + 0];
    if (n0 + c + 1 < N) v1 = p[n0 + c + 1];
    if (n0 + c + 2 < N) v2 = p[n0 + c + 2];
  }
  T[r][c] = v0; T[r][c + 1] = v1; T[r][c + 2] = v2; T[r][c + 3] = v3;
  __syncthreads();
  const int nl = tid >> 3, kl = (tid & 7) * 4;
  const int n = n0 + nl;
  if (n < Npad) {
    short4_t o;
    o.x = (n < N) ? f2bf(T[kl + 0][nl]) : (short)0;
    o.y = (n < N) ? f2bf(T[kl + 1][nl]) : (short)0;
    o.z = (n < N) ? f2bf(T[kl + 2][nl]) : (short)0;
    o.w = (n < N) ? f2bf(T[kl + 3][nl]) : (short)0;
    *(short4_t*)&BT[(size_t)n * K + k0 + kl] = o;
  }
}

// ---------------------------------------------------------------------------
// MFMA main loop: 128x128 tile, BK=64, XOR-swizzled LDS (verified 0 conflicts).
// Per-lane global base pointers precomputed by caller (enables row gather).
// ---------------------------------------------------------------------------
__device__ __forceinline__ void mfma_mainloop(const short* aB[4], const short* bB[4],
                                              short* As, short* Bs,
                                              f32x4 acc[4][4],
                                              int K, int w, int lane) {
  const int quad = lane >> 4, ln = lane & 15;
  const int wm = w >> 1, wn = w & 1;
  const int l7 = ln & 7;
  for (int kt = 0; kt < K; kt += 64) {
#pragma unroll
    for (int i = 0; i < 4; ++i) {
      const int row = w * 32 + i * 8;
      __builtin_amdgcn_global_load_lds(
          (const __attribute__((address_space(1))) void*)(aB[i] + kt),
          (__attribute__((address_space(3))) void*)(As + row * 64), 16, 0, 0);
      __builtin_amdgcn_global_load_lds(
          (const __attribute__((address_space(1))) void*)(bB[i] + kt),
          (__attribute__((address_space(3))) void*)(Bs + row * 64), 16, 0, 0);
    }
    __syncthreads();
#pragma unroll
    for (int ks = 0; ks < 2; ++ks) {
      const int kcs = ks * 4 + quad;
      short8 af[4], bfr[4];
#pragma unroll
      for (int mt = 0; mt < 4; ++mt) {
        const int row = wm * 64 + mt * 16 + ln;
        af[mt] = *(const short8*)(As + ((row * 8 + (kcs ^ l7)) << 3));
      }
#pragma unroll
      for (int nt = 0; nt < 4; ++nt) {
        const int rowb = wn * 64 + nt * 16 + ln;
        bfr[nt] = *(const short8*)(Bs + ((rowb * 8 + (kcs ^ l7)) << 3));
      }
#pragma unroll
      for (int mt = 0; mt < 4; ++mt)
#pragma unroll
        for (int nt = 0; nt < 4; ++nt)
          acc[mt][nt] = __builtin_amdgcn_mfma_f32_16x16x32_bf16(
              af[mt], bfr[nt], acc[mt][nt], 0, 0, 0);
    }
    __syncthreads();
  }
}

// C/D layout: col = lane&15, row = (lane>>4)*4 + reg   [verified m89/m91]

// ---------------------------------------------------------------------------
// PROJ_ALL (one launch, 176 blocks): head proj (128 blocks, all rows) +
// tail1 proj on compacted rows (32 blocks, inline gather via rows1) +
// tail2 proj on compacted rows (16 blocks, via rows2).
// ---------------------------------------------------------------------------
__global__ __launch_bounds__(256) void proj_all(
    const short* __restrict__ xb,
    const short* __restrict__ WpT0, const short* __restrict__ WpT1,
    const short* __restrict__ WpT2,
    short* __restrict__ P0b, short* __restrict__ P1c, short* __restrict__ P2c,
    const int* __restrict__ rows1, const int* __restrict__ rows2,
    const int* __restrict__ counts) {
  int b = blockIdx.x;
  const short* BT; short* C; int N, r0, c0, cnt;
  const int* rowlist = nullptr;
  if (b < 128) {
    BT = WpT0; C = P0b; N = 1024;
    c0 = (b & 7) * 128; r0 = (b >> 3) * 128; cnt = NROWS;
  } else if (b < 160) {
    b -= 128; BT = WpT1; C = P1c; N = 256;
    c0 = (b & 1) * 128; r0 = (b >> 1) * 128; rowlist = rows1; cnt = counts[1];
  } else {
    b -= 160; BT = WpT2; C = P2c; N = 64;
    c0 = 0; r0 = b * 128; rowlist = rows2; cnt = counts[2];
  }
  if (r0 >= cnt) return;

  __shared__ short As[128 * 64];
  __shared__ short Bs[128 * 64];
  const int tid = threadIdx.x;
  const int w = tid >> 6, lane = tid & 63;
  const int quad = lane >> 4, ln = lane & 15;
  const int wm = w >> 1, wn = w & 1;
  const int rsub = lane >> 3;
  const int kc = (lane & 7) ^ rsub;
  const int K = 1024;

  const short* aB[4]; const short* bB[4];
#pragma unroll
  for (int i = 0; i < 4; ++i) {
    const int sl = r0 + w * 32 + i * 8 + rsub;
    const int ar = rowlist ? rowlist[sl < cnt ? sl : cnt - 1] : sl;
    aB[i] = xb + (size_t)ar * K + kc * 8;
    bB[i] = BT + (size_t)(c0 + w * 32 + i * 8 + rsub) * K + kc * 8;
  }

  f32x4 acc[4][4];
  const f32x4 zero = {0.f, 0.f, 0.f, 0.f};
#pragma unroll
  for (int i = 0; i < 4; ++i)
#pragma unroll
    for (int j = 0; j < 4; ++j) acc[i][j] = zero;
  mfma_mainloop(aB, bB, As, Bs, acc, K, w, lane);
#pragma unroll
  for (int mt = 0; mt < 4; ++mt)
#pragma unroll
    for (int r = 0; r < 4; ++r) {
      const int grow = r0 + wm * 64 + mt * 16 + quad * 4 + r;
#pragma unroll
      for (int nt = 0; nt < 4; ++nt) {
        const int cg = c0 + wn * 64 + nt * 16 + ln;
        if (cg < N) C[(size_t)grow * N + cg] = f2bf(acc[mt][nt][r]);
      }
    }
}

// ---------------------------------------------------------------------------
// LOGIT_ALL with XCD-aware work partitioning.
// xcd = blockIdx & 7 (dispatch round-robins XCDs). Each XCD owns an exclusive
// contiguous slice of col-splits so its B slice stays L2-resident:
//   head:  10 cs/XCD (2.5 MB B-slice), 16 rb, rb-slow/cs-fast  -> 1280 blocks
//   tail1: 30 cs/XCD (1.9 MB), 16 rb                           -> 3840 blocks
//   tail2: 51 cs/XCD (816 KB), 16 rb                           -> 6528 blocks
// Emits per-(row, 128-col-split) sum-of-exp partials.
// ---------------------------------------------------------------------------
#define HB  1280
#define T1B 3840
#define T2B 6528

__global__ __launch_bounds__(256) void logit_all(
    const short* __restrict__ P0b, const short* __restrict__ WlT0,
    const float* __restrict__ bl0, float* __restrict__ psh,
    const short* __restrict__ P1c, const short* __restrict__ WlT1,
    const float* __restrict__ bl1, float* __restrict__ ps1,
    const short* __restrict__ P2c, const short* __restrict__ WlT2,
    const float* __restrict__ bl2, float* __restrict__ ps2,
    const int* __restrict__ counts) {
  int b = blockIdx.x;
  const short* A; const short* BT; const float* bias; float* ps;
  int K, Ncols, nsplit, rb, cs, cnt;
  if (b < HB) {
    const int xcd = b & 7, j = b >> 3;
    rb = j / 10; cs = xcd * 10 + j % 10;
    if (cs >= 79) return;
    A = P0b; BT = WlT0; bias = bl0; ps = psh;
    K = 1024; Ncols = 10000; nsplit = 79; cnt = NROWS;
  } else if ((b -= HB) < T1B) {
    const int xcd = b & 7, j = b >> 3;
    rb = j / 30; cs = xcd * 30 + j % 30;
    if (cs >= 235) return;
    A = P1c; BT = WlT1; bias = bl1; ps = ps1;
    K = 256; Ncols = 30000; nsplit = 235; cnt = counts[1];
  } else {
    b -= T1B;
    const int xcd = b & 7, j = b >> 3;
    rb = j / 51; cs = xcd * 51 + j % 51;
    if (cs >= 407) return;
    A = P2c; BT = WlT2; bias = bl2; ps = ps2;
    K = 64; Ncols = 52000; nsplit = 407; cnt = counts[2];
  }
  const int r0 = rb * 128, c0 = cs * 128;
  if (r0 >= cnt) return;

  __shared__ short As[128 * 64];
  __shared__ short Bs[128 * 64];
  __shared__ float psL[2][128];
  const int tid = threadIdx.x;
  const int w = tid >> 6, lane = tid & 63;
  const int quad = lane >> 4, ln = lane & 15;
  const int wm = w >> 1, wn = w & 1;
  const int rsub = lane >> 3;
  const int kc = (lane & 7) ^ rsub;

  const short* aB[4]; const short* bB[4];
#pragma unroll
  for (int i = 0; i < 4; ++i) {
    aB[i] = A + (size_t)(r0 + w * 32 + i * 8 + rsub) * K + kc * 8;
    bB[i] = BT + (size_t)(c0 + w * 32 + i * 8 + rsub) * K + kc * 8;
  }

  f32x4 acc[4][4];
  const f32x4 zero = {0.f, 0.f, 0.f, 0.f};
#pragma unroll
  for (int i = 0; i < 4; ++i)
#pragma unroll
    for (int j = 0; j < 4; ++j) acc[i][j] = zero;
  mfma_mainloop(aB, bB, As, Bs, acc, K, w, lane);

  float bv[4];
#pragma unroll
  for (int nt = 0; nt < 4; ++nt) {
    const int cg = c0 + wn * 64 + nt * 16 + ln;
    bv[nt] = (cg < Ncols) ? bias[cg] : -1.0e30f;  // exp underflows to 0 for pad
  }
#pragma unroll
  for (int mt = 0; mt < 4; ++mt)
#pragma unroll
    for (int r = 0; r < 4; ++r) {
      float s = 0.f;
#pragma unroll
      for (int nt = 0; nt < 4; ++nt)
        s += __expf(acc[mt][nt][r] + bv[nt]);
#pragma unroll
      for (int off = 1; off < 16; off <<= 1) s += __shfl_xor(s, off, 64);
      if (ln == 0) psL[wn][wm * 64 + mt * 16 + quad * 4 + r] = s;
    }
  __syncthreads();
  if (tid < 128)
    ps[(size_t)(r0 + tid) * nsplit + cs] = psL[0][tid] + psL[1][tid];
}

// ---------------------------------------------------------------------------
// FINALIZE: one wave per row. Target dots use the bf16 transposed weights
// (contiguous rows) instead of strided fp32 columns.
// ---------------------------------------------------------------------------
__global__ __launch_bounds__(256) void finalize(
    const short* __restrict__ P0b, const short* __restrict__ P1c,
    const short* __restrict__ P2c,
    const short* __restrict__ WlT0, const float* __restrict__ bl0,
    const short* __restrict__ WlT1, const float* __restrict__ bl1,
    const short* __restrict__ WlT2, const float* __restrict__ bl2,
    const float* __restrict__ Wc, const float* __restrict__ bc,
    const int* __restrict__ y, const int* __restrict__ slot_of_row,
    const float* __restrict__ psh, const float* __restrict__ ps1,
    const float* __restrict__ ps2, float* __restrict__ out) {
  const int lane = threadIdx.x & 63;
  const int row = blockIdx.x * 4 + (threadIdx.x >> 6);

  float a0 = 0.f, a1 = 0.f;
  for (int k = lane; k < HID; k += 64) {
    const float p = bf2f(P0b[(size_t)row * HID + k]);
    a0 += p * Wc[2 * k];
    a1 += p * Wc[2 * k + 1];
  }
  a0 = wave_sum(a0);
  a1 = wave_sum(a1);
  const float cl0 = a0 + bc[0], cl1 = a1 + bc[1];

  float S = 0.f;
  for (int i = lane; i < 79; i += 64) S += psh[(size_t)row * 79 + i];
  S = wave_sum(S) + __expf(cl0) + __expf(cl1);
  const float lse = logf(S);

  const int yy = y[row];
  float nll;
  if (yy < 10000) {
    const short* pr = P0b + (size_t)row * 1024;
    const short* wr = WlT0 + (size_t)yy * 1024;
    float a = 0.f;
    for (int kk = lane * 4; kk < 1024; kk += 256) {
      const short4_t p = *(const short4_t*)(pr + kk);
      const short4_t wv = *(const short4_t*)(wr + kk);
      a += bf2f(p.x) * bf2f(wv.x) + bf2f(p.y) * bf2f(wv.y)
         + bf2f(p.z) * bf2f(wv.z) + bf2f(p.w) * bf2f(wv.w);
    }
    a = wave_sum(a);
    nll = -((a + bl0[yy]) - lse);
  } else if (yy < 20000) {
    const int t = yy - 10000;
    const int slot = slot_of_row[row];
    float S1 = 0.f;
    for (int i = lane; i < 235; i += 64) S1 += ps1[(size_t)slot * 235 + i];
    S1 = wave_sum(S1);
    const short* pr = P1c + (size_t)slot * 256;
    const short* wr = WlT1 + (size_t)t * 256;
    const int kk = lane * 4;
    const short4_t p = *(const short4_t*)(pr + kk);
    const short4_t wv = *(const short4_t*)(wr + kk);
    float a = bf2f(p.x) * bf2f(wv.x) + bf2f(p.y) * bf2f(wv.y)
            + bf2f(p.z) * bf2f(wv.z) + bf2f(p.w) * bf2f(wv.w);
    a = wave_sum(a);
    nll = -((cl1 - lse) + ((a + bl1[t]) - logf(S1)));
  } else {
    const int t = yy - 20000;
    const int slot = slot_of_row[row];
    float S2 = 0.f;
    for (int i = lane; i < 407; i += 64) S2 += ps2[(size_t)slot * 407 + i];
    S2 = wave_sum(S2);
    float a = 0.f;
    if (lane < 16) {
      const short* pr = P2c + (size_t)slot * 64;
      const short* wr = WlT2 + (size_t)t * 64;
      const int kk = lane * 4;
      const short4_t p = *(const short4_t*)(pr + kk);
      const short4_t wv = *(const short4_t*)(wr + kk);
      a = bf2f(p.x) * bf2f(wv.x) + bf2f(p.y) * bf2f(wv.y)
        + bf2f(p.z) * bf2f(wv.z) + bf2f(p.w) * bf2f(wv.w);
    }
    a = wave_sum(a);
    nll = -((cl0 - lse) + ((a + bl2[t]) - logf(S2)));
  }
  if (lane == 0) out[row] = nll;
}

// ---------------------------------------------------------------------------
extern "C" void kernel_launch(void* const* d_in, const int* in_sizes, int n_in,
                              void* d_out, int out_size, void* d_ws, size_t ws_size,
                              hipStream_t stream) {
  const float* x   = (const float*)d_in[0];
  const int*   y   = (const int*)d_in[1];
  const float* Wp0 = (const float*)d_in[2];
  const float* Wp1 = (const float*)d_in[3];
  const float* Wp2 = (const float*)d_in[4];
  const float* Wl0 = (const float*)d_in[5];
  const float* bl0 = (const float*)d_in[6];
  const float* Wl1 = (const float*)d_in[7];
  const float* bl1 = (const float*)d_in[8];
  const float* Wl2 = (const float*)d_in[9];
  const float* bl2 = (const float*)d_in[10];
  const float* Wc  = (const float*)d_in[11];
  const float* bc  = (const float*)d_in[12];
  float* out = (float*)d_out;

  float* fws = (float*)d_ws;
  float* psh = fws; fws += (size_t)NROWS * 79;
  float* ps1 = fws; fws += (size_t)NROWS * 235;
  float* ps2 = fws; fws += (size_t)NROWS * 407;
  int* iws = (int*)fws;
  int* counts      = iws; iws += 4;
  int* slot_of_row = iws; iws += NROWS;
  int* rows1       = iws; iws += NROWS;
  int* rows2       = iws; iws += NROWS;
  short* sp = (short*)iws;
  short* xb   = sp; sp += (size_t)NROWS * 1024;
  short* P0b  = sp; sp += (size_t)NROWS * 1024;
  short* P1c  = sp; sp += (size_t)NROWS * 256;
  short* P2c  = sp; sp += (size_t)NROWS * 64;
  short* WpT0 = sp; sp += (size_t)1024 * 1024;
  short* WpT1 = sp; sp += (size_t)256 * 1024;
  short* WpT2 = sp; sp += (size_t)128 * 1024;
  short* WlT0 = sp; sp += (size_t)10112 * 1024;
  short* WlT1 = sp; sp += (size_t)30080 * 256;
  short* WlT2 = sp; sp += (size_t)52096 * 64;

  dim3 blk(256);
  prep<<<dim3(24345), blk, 0, stream>>>(x, y, Wp0, Wp1, Wp2, Wl0, Wl1, Wl2,
                                        xb, counts, slot_of_row, rows1, rows2,
                                        WpT0, WpT1, WpT2, WlT0, WlT1, WlT2);
  proj_all<<<dim3(176), blk, 0, stream>>>(xb, WpT0, WpT1, WpT2, P0b, P1c, P2c,
                                          rows1, rows2, counts);
  logit_all<<<dim3(HB + T1B + T2B), blk, 0, stream>>>(
      P0b, WlT0, bl0, psh, P1c, WlT1, bl1, ps1, P2c, WlT2, bl2, ps2, counts);
  finalize<<<dim3(NROWS / 4), blk, 0, stream>>>(
      P0b, P1c, P2c, WlT0, bl0, WlT1, bl1, WlT2, bl2, Wc, bc, y, slot_of_row,
      psh, ps1, ps2, out);
}